// Round 1
// baseline (2584.155 us; speedup 1.0000x reference)
//
#include <hip/hip_runtime.h>
#include <hip/hip_bf16.h>
#include <cstdint>

#define VOCAB 28996
#define T_STEPS 1024
#define D_IN 256
#define HDIM 512

using f32x4 = __attribute__((ext_vector_type(4))) float;
using s16x8 = __attribute__((ext_vector_type(8))) short;

static __device__ __forceinline__ unsigned short f2bf(float f){
    unsigned u = __float_as_uint(f);
    u = u + 0x7FFFu + ((u >> 16) & 1u);   // round-to-nearest-even
    return (unsigned short)(u >> 16);
}

// ---------------------------------------------------------------------------
// Kernel 1: init hs buffer: row 0 = h0, rows 1..1024 = NaN sentinel
// ---------------------------------------------------------------------------
__global__ void init_hs_kernel(const float* __restrict__ h0, float* __restrict__ hs){
    const int col = threadIdx.x;          // 0..511
    const int row = blockIdx.x;           // 0..1024
    float v = (row == 0) ? h0[col] : __uint_as_float(0x7FC00001u);
    hs[(size_t)row * HDIM + col] = v;
}

// ---------------------------------------------------------------------------
// Kernel 2: xg = x @ w_ih^T + b_ih   ([1024 x 256] @ [256 -> 1536])  fp32
// grid (6, 128), block 256. Each WG: 256 i-cols x 8 t-rows.
// ---------------------------------------------------------------------------
__global__ void xg_kernel(const float* __restrict__ x, const float* __restrict__ w_ih,
                          const float* __restrict__ b_ih, float* __restrict__ xg){
    __shared__ float xs[8][D_IN];
    const int tid = threadIdx.x;
    const int i   = blockIdx.x * 256 + tid;   // 0..1535
    const int t0  = blockIdx.y * 8;
    #pragma unroll
    for (int r = 0; r < 8; ++r)
        xs[r][tid] = x[(size_t)(t0 + r) * D_IN + tid];
    __syncthreads();

    float acc[8] = {0.f,0.f,0.f,0.f,0.f,0.f,0.f,0.f};
    const float* wrow = w_ih + (size_t)i * D_IN;
    for (int d = 0; d < D_IN; d += 4){
        float4 w4 = *(const float4*)(wrow + d);
        #pragma unroll
        for (int r = 0; r < 8; ++r){
            acc[r] += w4.x * xs[r][d]   + w4.y * xs[r][d+1]
                    + w4.z * xs[r][d+2] + w4.w * xs[r][d+3];
        }
    }
    const float b = b_ih[i];
    #pragma unroll
    for (int r = 0; r < 8; ++r)
        xg[(size_t)(t0 + r) * (3*HDIM) + i] = acc[r] + b;
}

// ---------------------------------------------------------------------------
// Kernel 3: sequential GRU scan. 32 persistent WGs x 256 threads.
// WG w owns j in [16w, 16w+16). Weights (rows j, 512+j, 1024+j of w_hh,
// fp32) live in registers: lane (j_loc, c) holds 3 x 8 float4 covering cols
// 4*(c+16s). Hidden state broadcast through hs[] with NaN-sentinel polling
// using relaxed agent-scope atomics (data-as-flag, dword-atomic).
// ---------------------------------------------------------------------------
__launch_bounds__(256)
__global__ void scan_kernel(const float* __restrict__ xg, const float* __restrict__ w_hh,
                            const float* __restrict__ b_hh, float* hs){
    const int tid = threadIdx.x;
    const int c   = tid & 15;       // column-chunk selector
    const int jl  = tid >> 4;       // 0..15
    const int j   = blockIdx.x * 16 + jl;   // 0..511

    // -- load recurrent weights into registers (one-time) --
    float4 WR[8], WZ[8], WN[8];
    const float* wr = w_hh + (size_t)j * HDIM;
    const float* wz = w_hh + (size_t)(HDIM   + j) * HDIM;
    const float* wn = w_hh + (size_t)(2*HDIM + j) * HDIM;
    #pragma unroll
    for (int s = 0; s < 8; ++s){
        const int off = 4 * (c + 16 * s);
        WR[s] = *(const float4*)(wr + off);
        WZ[s] = *(const float4*)(wz + off);
        WN[s] = *(const float4*)(wn + off);
    }
    float bhr = 0.f, bhz = 0.f, bhn = 0.f;
    if (c == 0){ bhr = b_hh[j]; bhz = b_hh[HDIM + j]; bhn = b_hh[2*HDIM + j]; }

    __shared__ float h_lds[HDIM];
    const unsigned SENT = 0x7FC00001u;

    for (int t = 0; t < T_STEPS; ++t){
        // xg prefetch (independent of poll; latency hides under the spin)
        float xr = 0.f, xz = 0.f, xn = 0.f;
        if (c == 0){
            const float* xgt = xg + (size_t)t * (3*HDIM);
            xr = xgt[j]; xz = xgt[HDIM + j]; xn = xgt[2*HDIM + j];
        }
        // -- poll h_t (each thread owns 2 floats) --
        unsigned long long* src = (unsigned long long*)(hs + (size_t)t * HDIM + 2 * tid);
        unsigned long long vv;
        do {
            vv = __hip_atomic_load(src, __ATOMIC_RELAXED, __HIP_MEMORY_SCOPE_AGENT);
        } while ((unsigned)vv == SENT || (unsigned)(vv >> 32) == SENT);
        h_lds[2*tid]     = __uint_as_float((unsigned)vv);
        h_lds[2*tid + 1] = __uint_as_float((unsigned)(vv >> 32));
        __syncthreads();

        // -- partial matvec: 96 FMAs/lane, 6 independent chains --
        float ar0=0.f, ar1=0.f, az0=0.f, az1=0.f, an0=0.f, an1=0.f;
        #pragma unroll
        for (int s = 0; s < 8; s += 2){
            float4 h4 = *(const float4*)&h_lds[4 * (c + 16 * s)];
            ar0 += WR[s].x*h4.x + WR[s].y*h4.y + WR[s].z*h4.z + WR[s].w*h4.w;
            az0 += WZ[s].x*h4.x + WZ[s].y*h4.y + WZ[s].z*h4.z + WZ[s].w*h4.w;
            an0 += WN[s].x*h4.x + WN[s].y*h4.y + WN[s].z*h4.z + WN[s].w*h4.w;
            float4 h5 = *(const float4*)&h_lds[4 * (c + 16 * (s+1))];
            ar1 += WR[s+1].x*h5.x + WR[s+1].y*h5.y + WR[s+1].z*h5.z + WR[s+1].w*h5.w;
            az1 += WZ[s+1].x*h5.x + WZ[s+1].y*h5.y + WZ[s+1].z*h5.z + WZ[s+1].w*h5.w;
            an1 += WN[s+1].x*h5.x + WN[s+1].y*h5.y + WN[s+1].z*h5.z + WN[s+1].w*h5.w;
        }
        float ar = ar0 + ar1, az = az0 + az1, an = an0 + an1;
        #pragma unroll
        for (int m = 1; m < 16; m <<= 1){
            ar += __shfl_xor(ar, m);
            az += __shfl_xor(az, m);
            an += __shfl_xor(an, m);
        }
        if (c == 0){
            const float r = 1.0f / (1.0f + __expf(-(xr + ar + bhr)));
            const float z = 1.0f / (1.0f + __expf(-(xz + az + bhz)));
            const float nn = xn + r * (an + bhn);
            const float e  = __expf(2.0f * nn);
            const float th = 1.0f - 2.0f / (e + 1.0f);   // tanh, inf-safe
            const float hnew = (1.0f - z) * th + z * h_lds[j];
            __hip_atomic_store(hs + (size_t)(t + 1) * HDIM + j, hnew,
                               __ATOMIC_RELAXED, __HIP_MEMORY_SCOPE_AGENT);
        }
        __syncthreads();   // protect h_lds before next iteration overwrites
    }
}

// ---------------------------------------------------------------------------
// Kernel 4: preds = hs[1..1024] @ w_pred^T + b_pred  (bf16 MFMA, fp32 out)
// 128x128 tile, BK=32, 4 waves (2x2), each wave 64x64 = 4x4 frags 16x16x32.
// grid (8, 227); N-tail guarded.
// ---------------------------------------------------------------------------
__launch_bounds__(256)
__global__ void pred_gemm_kernel(const float* __restrict__ hs, const float* __restrict__ w_pred,
                                 const float* __restrict__ b_pred, float* __restrict__ out){
    __shared__ unsigned short As[128 * 32];
    __shared__ unsigned short Bs[128 * 32];
    const int tid   = threadIdx.x;
    const int mtile = blockIdx.x;    // 0..7
    const int ntile = blockIdx.y;    // 0..226
    const int row  = tid >> 1, half = tid & 1;
    const int wave = tid >> 6, lane = tid & 63;
    const int wm = wave >> 1, wn = wave & 1;
    const int lr = lane & 15, kq = lane >> 4;

    f32x4 acc[4][4] = {};

    const float* Abase = hs + HDIM /*skip h0 row*/ + (size_t)(mtile * 128 + row) * HDIM;
    const int    nrow  = ntile * 128 + row;
    const float* Bbase = w_pred + (size_t)nrow * HDIM;

    for (int k0 = 0; k0 < HDIM; k0 += 32){
        // -- stage A tile (fp32 -> bf16) --
        {
            const float* srcp = Abase + k0 + half * 16;
            unsigned short* dst = &As[row * 32 + half * 16];
            #pragma unroll
            for (int q = 0; q < 4; ++q){
                float4 v = *(const float4*)(srcp + 4 * q);
                uint2 p;
                p.x = (unsigned)f2bf(v.x) | ((unsigned)f2bf(v.y) << 16);
                p.y = (unsigned)f2bf(v.z) | ((unsigned)f2bf(v.w) << 16);
                *(uint2*)(dst + 4 * q) = p;
            }
        }
        // -- stage B tile (guarded) --
        {
            unsigned short* dst = &Bs[row * 32 + half * 16];
            if (nrow < VOCAB){
                const float* srcp = Bbase + k0 + half * 16;
                #pragma unroll
                for (int q = 0; q < 4; ++q){
                    float4 v = *(const float4*)(srcp + 4 * q);
                    uint2 p;
                    p.x = (unsigned)f2bf(v.x) | ((unsigned)f2bf(v.y) << 16);
                    p.y = (unsigned)f2bf(v.z) | ((unsigned)f2bf(v.w) << 16);
                    *(uint2*)(dst + 4 * q) = p;
                }
            } else {
                uint2 zz; zz.x = 0u; zz.y = 0u;
                #pragma unroll
                for (int q = 0; q < 4; ++q) *(uint2*)(dst + 4 * q) = zz;
            }
        }
        __syncthreads();

        const unsigned short* Ab = &As[(wm * 64 + lr) * 32 + kq * 8];
        const unsigned short* Bb = &Bs[(wn * 64 + lr) * 32 + kq * 8];
        s16x8 af[4], bf[4];
        #pragma unroll
        for (int mf = 0; mf < 4; ++mf) af[mf] = *(const s16x8*)(Ab + mf * 16 * 32);
        #pragma unroll
        for (int nf = 0; nf < 4; ++nf) bf[nf] = *(const s16x8*)(Bb + nf * 16 * 32);
        #pragma unroll
        for (int mf = 0; mf < 4; ++mf){
            #pragma unroll
            for (int nf = 0; nf < 4; ++nf){
                acc[mf][nf] = __builtin_amdgcn_mfma_f32_16x16x32_bf16(af[mf], bf[nf], acc[mf][nf], 0, 0, 0);
            }
        }
        __syncthreads();
    }

    // -- epilogue: C[m][n] += b_pred[n]; D layout col=lane&15, row=(lane>>4)*4+q --
    #pragma unroll
    for (int nf = 0; nf < 4; ++nf){
        const int n = ntile * 128 + wn * 64 + nf * 16 + lr;
        if (n >= VOCAB) continue;
        const float bp = b_pred[n];
        #pragma unroll
        for (int mf = 0; mf < 4; ++mf){
            const int m = mtile * 128 + wm * 64 + mf * 16 + kq * 4;
            #pragma unroll
            for (int q = 0; q < 4; ++q){
                out[(size_t)(m + q) * VOCAB + n] = acc[mf][nf][q] + bp;
            }
        }
    }
}

// ---------------------------------------------------------------------------
extern "C" void kernel_launch(void* const* d_in, const int* in_sizes, int n_in,
                              void* d_out, int out_size, void* d_ws, size_t ws_size,
                              hipStream_t stream){
    const float* x      = (const float*)d_in[0];
    const float* h0     = (const float*)d_in[1];
    const float* w_ih   = (const float*)d_in[2];
    const float* w_hh   = (const float*)d_in[3];
    const float* b_ih   = (const float*)d_in[4];
    const float* b_hh   = (const float*)d_in[5];
    const float* w_pred = (const float*)d_in[6];
    const float* b_pred = (const float*)d_in[7];
    float* out = (float*)d_out;

    float* xg = (float*)d_ws;                       // 1024*1536 fp32 = 6.29 MB
    float* hs = xg + (size_t)T_STEPS * (3*HDIM);    // 1025*512  fp32 = 2.10 MB

    hipLaunchKernelGGL(init_hs_kernel, dim3(T_STEPS + 1), dim3(HDIM), 0, stream, h0, hs);
    hipLaunchKernelGGL(xg_kernel,      dim3(6, 128),      dim3(256),  0, stream, x, w_ih, b_ih, xg);
    hipLaunchKernelGGL(scan_kernel,    dim3(32),          dim3(256),  0, stream, xg, w_hh, b_hh, hs);
    hipLaunchKernelGGL(pred_gemm_kernel, dim3(8, 227),    dim3(256),  0, stream, hs, w_pred, b_pred, out);
}